// Round 3
// baseline (694.512 us; speedup 1.0000x reference)
//
#include <hip/hip_runtime.h>

#define N 8192
#define D 1024

typedef short bf16x8 __attribute__((ext_vector_type(8)));
typedef float f32x4 __attribute__((ext_vector_type(4)));
typedef unsigned short u16;

__device__ __forceinline__ u16 f2bf(float f) {
  unsigned u = __float_as_uint(f);
  u += 0x7FFF + ((u >> 16) & 1);   // RNE to bf16
  return (u16)(u >> 16);
}
__device__ __forceinline__ float bf2f(u16 h) {
  return __uint_as_float(((unsigned)h) << 16);
}

__device__ __forceinline__ void gload_lds16(const void* g, const void* l) {
  __builtin_amdgcn_global_load_lds(
      (const __attribute__((address_space(1))) void*)g,
      (__attribute__((address_space(3))) void*)l, 16, 0, 0);
}

// Swizzled [rows][32] bf16 tile, 64 B/row, 4x 16B chunks per row.
// Physical chunk = logical chunk ^ ((row>>1)&3). Involution; both the
// stage (global-source side) and the ds_read side apply it.
__device__ __forceinline__ int swz_byte(int row, int logical_chunk) {
  return row * 64 + ((logical_chunk ^ ((row >> 1) & 3)) << 4);
}

// ---------------- K0: split X (fp32) into Hi/Lo bf16 ----------------
__global__ __launch_bounds__(256) void k_split(const float* __restrict__ X,
                                               u16* __restrict__ hi,
                                               u16* __restrict__ lo) {
  int i = blockIdx.x * 256 + threadIdx.x;   // float4 index, total N*D/4
  float4 x = ((const float4*)X)[i];
  u16 h0 = f2bf(x.x), h1 = f2bf(x.y), h2 = f2bf(x.z), h3 = f2bf(x.w);
  ushort4 hv = {h0, h1, h2, h3};
  ushort4 lv = {f2bf(x.x - bf2f(h0)), f2bf(x.y - bf2f(h1)),
                f2bf(x.z - bf2f(h2)), f2bf(x.w - bf2f(h3))};
  ((ushort4*)hi)[i] = hv;
  ((ushort4*)lo)[i] = lv;
}

// ---------------- K0b: transpose Xhi [N][D] -> XT [D][N] ----------------
__global__ __launch_bounds__(256) void k_transpose(const u16* __restrict__ Xh,
                                                   u16* __restrict__ XT) {
  __shared__ u16 t[32][33];
  const int jt = blockIdx.y * 32, dt = blockIdx.x * 32;
  const int c = threadIdx.x & 31, rg = threadIdx.x >> 5;   // rg in 0..7
#pragma unroll
  for (int k = 0; k < 4; ++k) {
    int r = rg * 4 + k;
    t[r][c] = Xh[(size_t)(jt + r) * D + dt + c];
  }
  __syncthreads();
#pragma unroll
  for (int k = 0; k < 4; ++k) {
    int d = rg * 4 + k;
    XT[(size_t)(dt + d) * N + jt + c] = t[c][d];
  }
}

// ------- K1: S = X X^T, symmetric: only upper-tri 128x128 blocks --------
__global__ __launch_bounds__(256) void k_qkt(const u16* __restrict__ Xh,
                                             const u16* __restrict__ Xl,
                                             float* __restrict__ S) {
  __shared__ union {
    u16 stage[4][128 * 32];     // Ah, Al, Bh, Bl  (32 KiB)
    float tbuf[128][64];        // transpose bounce (32 KiB, XOR-swizzled)
  } sm;
  u16* Ah = sm.stage[0];
  u16* Al = sm.stage[1];
  u16* Bh = sm.stage[2];
  u16* Bl = sm.stage[3];

  const int tid = threadIdx.x, wid = tid >> 6, lane = tid & 63;

  // map linear block id -> (bi, bj), bi <= bj, over 64x64 block grid
  int t = blockIdx.x, bi = 0;
  while (t >= 64 - bi) { t -= 64 - bi; ++bi; }
  const int bj = bi + t;
  const int brow = bi * 128, bcol = bj * 128;

  const int wr = wid >> 1, wc = wid & 1;
  const int fr = lane & 15;
  const int c0 = lane >> 4;          // logical 16B chunk for ds_read

  f32x4 acc[4][4] = {};

  for (int kt = 0; kt < D; kt += 32) {
    __syncthreads();
#pragma unroll
    for (int c = 0; c < 2; ++c) {
      int chunk = wid * 2 + c;               // 0..7 (1024B chunks)
      int ebyte = chunk * 1024 + lane * 16;  // linear LDS dest byte
      int row = ebyte >> 6;
      int pc = (ebyte >> 4) & 3;             // physical chunk slot
      int col = (pc ^ ((row >> 1) & 3)) * 8; // logical col staged there
      size_t ga = (size_t)(brow + row) * D + kt + col;
      size_t gb = (size_t)(bcol + row) * D + kt + col;
      gload_lds16(Xh + ga, (const char*)Ah + ebyte);
      gload_lds16(Xl + ga, (const char*)Al + ebyte);
      gload_lds16(Xh + gb, (const char*)Bh + ebyte);
      gload_lds16(Xl + gb, (const char*)Bl + ebyte);
    }
    __syncthreads();

    bf16x8 ah[4], al[4], bh[4], bl[4];
#pragma unroll
    for (int m = 0; m < 4; ++m) {
      int row = wr * 64 + m * 16 + fr;
      int pb = swz_byte(row, c0);
      ah[m] = *(const bf16x8*)((const char*)Ah + pb);
      al[m] = *(const bf16x8*)((const char*)Al + pb);
    }
#pragma unroll
    for (int n = 0; n < 4; ++n) {
      int row = wc * 64 + n * 16 + fr;
      int pb = swz_byte(row, c0);
      bh[n] = *(const bf16x8*)((const char*)Bh + pb);
      bl[n] = *(const bf16x8*)((const char*)Bl + pb);
    }
#pragma unroll
    for (int m = 0; m < 4; ++m)
#pragma unroll
      for (int n = 0; n < 4; ++n) {
        acc[m][n] = __builtin_amdgcn_mfma_f32_16x16x32_bf16(ah[m], bh[n], acc[m][n], 0, 0, 0);
        acc[m][n] = __builtin_amdgcn_mfma_f32_16x16x32_bf16(ah[m], bl[n], acc[m][n], 0, 0, 0);
        acc[m][n] = __builtin_amdgcn_mfma_f32_16x16x32_bf16(al[m], bh[n], acc[m][n], 0, 0, 0);
      }
  }

  const int rr = (lane >> 4) * 4;
  // direct tile write: S[brow..][bcol..]
#pragma unroll
  for (int m = 0; m < 4; ++m)
#pragma unroll
    for (int n = 0; n < 4; ++n)
#pragma unroll
      for (int r = 0; r < 4; ++r) {
        int row = brow + wr * 64 + m * 16 + rr + r;
        int col = bcol + wc * 64 + n * 16 + fr;
        S[(size_t)row * N + col] = acc[m][n][r];
      }

  // transposed tile write for off-diagonal blocks: S[bcol..][brow..]
  if (bi != bj) {
#pragma unroll
    for (int pass = 0; pass < 2; ++pass) {
      __syncthreads();                 // stage/tbuf reuse + prior reads done
      if (wr == pass) {
#pragma unroll
        for (int m = 0; m < 4; ++m)
#pragma unroll
          for (int n = 0; n < 4; ++n) {
            f32x4 v = acc[m][n];
            int c = wc * 64 + n * 16 + fr;
            int inner = ((m * 16 + rr) * 4) ^ ((c & 15) << 4);
            *(f32x4*)((char*)&sm.tbuf[c][0] + inner) = v;
          }
      }
      __syncthreads();
#pragma unroll
      for (int i = 0; i < 8; ++i) {
        int idx = i * 256 + tid;         // 2048 float4 = 128 cols x 16 quads
        int c = idx >> 4;                // 0..127
        int kq = idx & 15;               // 0..15
        int inner = (kq * 16) ^ ((c & 15) << 4);
        float4 v4 = *(const float4*)((const char*)&sm.tbuf[c][0] + inner);
        *(float4*)&S[(size_t)(bcol + c) * N + brow + pass * 64 + kq * 4] = v4;
      }
    }
  }
}

// ---------------- K2: in-place row softmax (+ optional bf16 P copy) -----
template <int WRITE_PB>
__global__ __launch_bounds__(256) void k_softmax(float* __restrict__ S,
                                                 u16* __restrict__ Pb) {
  const int row = blockIdx.x;
  float* p = S + (size_t)row * N;
  const int tid = threadIdx.x;
  const int wid = tid >> 6, lane = tid & 63;
  __shared__ float red[4];

  float4 v[8];
  float m = -INFINITY;
#pragma unroll
  for (int i = 0; i < 8; ++i) {
    int idx = i * 256 + tid;              // float4 index within row
    float4 x = ((const float4*)p)[idx];
    if ((row >> 2) == idx) ((float*)&x)[row & 3] = -INFINITY;  // exclude diag
    v[i] = x;
    m = fmaxf(m, fmaxf(fmaxf(x.x, x.y), fmaxf(x.z, x.w)));
  }
#pragma unroll
  for (int off = 32; off > 0; off >>= 1) m = fmaxf(m, __shfl_xor(m, off));
  if (lane == 0) red[wid] = m;
  __syncthreads();
  m = fmaxf(fmaxf(red[0], red[1]), fmaxf(red[2], red[3]));

  float s = 0.f;
#pragma unroll
  for (int i = 0; i < 8; ++i) {
    float4 e;
    e.x = __expf(v[i].x - m);
    e.y = __expf(v[i].y - m);
    e.z = __expf(v[i].z - m);
    e.w = __expf(v[i].w - m);
    v[i] = e;
    s += e.x + e.y + e.z + e.w;
  }
#pragma unroll
  for (int off = 32; off > 0; off >>= 1) s += __shfl_xor(s, off);
  __syncthreads();                        // red[] reuse
  if (lane == 0) red[wid] = s;
  __syncthreads();
  s = red[0] + red[1] + red[2] + red[3];
  float inv = 1.0f / s;
#pragma unroll
  for (int i = 0; i < 8; ++i) {
    int idx = i * 256 + tid;
    float4 x = v[i];
    x.x *= inv; x.y *= inv; x.z *= inv; x.w *= inv;
    ((float4*)p)[idx] = x;
    if (WRITE_PB) {
      ushort4 h = {f2bf(x.x), f2bf(x.y), f2bf(x.z), f2bf(x.w)};
      ((ushort4*)(Pb + (size_t)row * N))[idx] = h;
    }
  }
}

// -------- K3: out = P @ X. BM=128 rows, BN=256 cols, 512 threads --------
template <int BF16P>
__global__ __launch_bounds__(512, 4) void k_pv(const float* __restrict__ P,
                                               const u16* __restrict__ Pb,
                                               const u16* __restrict__ XT,
                                               float* __restrict__ Out) {
  __shared__ u16 As[128 * 32];   // 8 KiB
  __shared__ u16 Bs[256 * 32];   // 16 KiB
  const int tid = threadIdx.x, wid = tid >> 6, lane = tid & 63;
  const int brow = blockIdx.y * 128;   // rows of P / out
  const int bcol = blockIdx.x * 256;   // cols of out (d)
  const int wr = wid >> 2, wc = wid & 3;   // 2 x 4 wave grid, 64x64 each
  const int fr = lane & 15;
  const int c0 = lane >> 4;

  f32x4 acc[4][4] = {};

  for (int kt = 0; kt < N; kt += 32) {
    __syncthreads();
    // stage B = XT[bcol..+256][kt..+32]: 16 chunks of 1024B, 2 per wave
#pragma unroll
    for (int c = 0; c < 2; ++c) {
      int chunk = wid * 2 + c;
      int ebyte = chunk * 1024 + lane * 16;
      int row = ebyte >> 6;
      int pc = (ebyte >> 4) & 3;
      int col = (pc ^ ((row >> 1) & 3)) * 8;
      gload_lds16(XT + (size_t)(bcol + row) * N + kt + col, (const char*)Bs + ebyte);
    }
    // stage A = P[brow..+128][kt..+32]: 8 chunks, 1 per wave
    if (BF16P) {
      int ebyte = wid * 1024 + lane * 16;
      int row = ebyte >> 6;
      int pc = (ebyte >> 4) & 3;
      int col = (pc ^ ((row >> 1) & 3)) * 8;
      gload_lds16(Pb + (size_t)(brow + row) * N + kt + col, (const char*)As + ebyte);
    } else {
      // fp32 -> bf16 reg-staged into the swizzled layout
#pragma unroll
      for (int i = 0; i < 2; ++i) {
        int idx = i * 512 + tid;           // float4 index in 128x32 tile
        int e = idx * 4;
        int row = e >> 5, col = e & 31;
        float4 x = *(const float4*)(P + (size_t)(brow + row) * N + kt + col);
        ushort4 h = {f2bf(x.x), f2bf(x.y), f2bf(x.z), f2bf(x.w)};
        int inner = (col * 2) ^ (((row >> 1) & 3) << 4);
        *(ushort4*)((char*)As + row * 64 + inner) = h;
      }
    }
    __syncthreads();

    bf16x8 a[4], b[4];
#pragma unroll
    for (int m = 0; m < 4; ++m) {
      int row = wr * 64 + m * 16 + fr;
      a[m] = *(const bf16x8*)((const char*)As + swz_byte(row, c0));
    }
#pragma unroll
    for (int n = 0; n < 4; ++n) {
      int row = wc * 64 + n * 16 + fr;
      b[n] = *(const bf16x8*)((const char*)Bs + swz_byte(row, c0));
    }
#pragma unroll
    for (int m = 0; m < 4; ++m)
#pragma unroll
      for (int n = 0; n < 4; ++n)
        acc[m][n] = __builtin_amdgcn_mfma_f32_16x16x32_bf16(a[m], b[n], acc[m][n], 0, 0, 0);
  }

  const int rr = (lane >> 4) * 4;
#pragma unroll
  for (int m = 0; m < 4; ++m)
#pragma unroll
    for (int n = 0; n < 4; ++n)
#pragma unroll
      for (int r = 0; r < 4; ++r) {
        int row = brow + wr * 64 + m * 16 + rr + r;
        int col = bcol + wc * 64 + n * 16 + fr;
        Out[(size_t)row * D + col] = acc[m][n][r];
      }
}

extern "C" void kernel_launch(void* const* d_in, const int* in_sizes, int n_in,
                              void* d_out, int out_size, void* d_ws, size_t ws_size,
                              hipStream_t stream) {
  const float* X = (const float*)d_in[0];
  float* out = (float*)d_out;
  float* attn = out + (size_t)N * D;        // second output: raw S, then softmaxed

  u16* Xh = (u16*)d_ws;                     // 16 MB
  u16* Xl = Xh + (size_t)N * D;             // 16 MB
  u16* XT = Xl + (size_t)N * D;             // 16 MB
  u16* Pb = XT + (size_t)N * D;             // 128 MB (optional)
  const bool usePb =
      ws_size >= ((size_t)N * D * 3 + (size_t)N * N) * sizeof(u16);

  k_split<<<(N * D / 4) / 256, 256, 0, stream>>>(X, Xh, Xl);
  k_transpose<<<dim3(D / 32, N / 32), 256, 0, stream>>>(Xh, XT);
  k_qkt<<<64 * 65 / 2, 256, 0, stream>>>(Xh, Xl, attn);
  if (usePb) {
    k_softmax<1><<<N, 256, 0, stream>>>(attn, Pb);
    k_pv<1><<<dim3(D / 256, N / 128), 512, 0, stream>>>(attn, Pb, XT, out);
  } else {
    k_softmax<0><<<N, 256, 0, stream>>>(attn, nullptr);
    k_pv<0><<<dim3(D / 256, N / 128), 512, 0, stream>>>(attn, nullptr, XT, out);
  }
}